// Round 18
// baseline (63.709 us; speedup 1.0000x reference)
//
#include <hip/hip_runtime.h>
#include <hip/hip_fp16.h>

#define W 256
#define NA 180
#define SWORDS_ALLOC 5440     // 21.76 KB -> ~7 blocks/CU

// Windowed tile: block = (angle a, batch n, cq in 0..3, rh in 0..1).
// Owns columns [cq*64, cq*64+63] and r in [r1lo + rh*t1, +t1).
// Stages only the bounding box of its taps (biased coords: x half = px+2, row = py+1).

__global__ __launch_bounds__(256) void radon_kernel(
    const float* __restrict__ x, const int* __restrict__ index_p,
    float* __restrict__ out)
{
    __shared__ unsigned sw[SWORDS_ALLOC];

    const int a = blockIdx.x;
    const int n = blockIdx.y;
    const int cq = blockIdx.z & 3;
    const int rh = blockIdx.z >> 2;
    const int tid = threadIdx.x;
    const int cl = tid & 63;         // local column (lane)
    const int s = tid >> 6;          // r-chunk (wave-uniform)

    const int index = *index_p;
    const int seg[6] = {1, 26, 51, 77, 102, 128};
    const int t0 = seg[4 - index];
    const int t1 = seg[4 - index + 1];
    const int r1lo = 128 - t1;
    const int r0lo = 128 - t0, r0hi = 127 + t0;
    const int rA = r1lo + rh * t1;   // this block's r-interval [rA, rA+t1)

    float sa, ca;
    sincosf((float)a * 0.017453292519943295f, &sa, &ca);

    // ---- window bounding box from the 4 (xc, rf) corners (wave-uniform) ----
    const float xcl = ((2.0f * (float)(cq * 64) + 1.0f) * (1.0f / 256.0f)) - 1.0f;
    const float xch = ((2.0f * (float)(cq * 64 + 63) + 1.0f) * (1.0f / 256.0f)) - 1.0f;
    const float rfl = (float)rA - 127.5f;
    const float rfh = rfl + (float)(t1 - 1);
    const float bxl = fmaf(128.0f * ca, xcl, 129.5f);
    const float bxh = fmaf(128.0f * ca, xch, 129.5f);
    const float byl = fmaf(-128.0f * sa, xcl, 128.5f);
    const float byh2 = fmaf(-128.0f * sa, xch, 128.5f);

    float ixmin = fminf(fminf(fmaf(sa, rfl, bxl), fmaf(sa, rfh, bxl)),
                        fminf(fmaf(sa, rfl, bxh), fmaf(sa, rfh, bxh)));
    float ixmax = fmaxf(fmaxf(fmaf(sa, rfl, bxl), fmaf(sa, rfh, bxl)),
                        fmaxf(fmaf(sa, rfl, bxh), fmaf(sa, rfh, bxh)));
    float iymin = fminf(fminf(fmaf(ca, rfl, byl), fmaf(ca, rfh, byl)),
                        fminf(fmaf(ca, rfl, byh2), fmaf(ca, rfh, byh2)));
    float iymax = fmaxf(fmaxf(fmaf(ca, rfl, byl), fmaf(ca, rfh, byl)),
                        fmaxf(fmaf(ca, rfl, byh2), fmaf(ca, rfh, byh2)));
    ixmin = __builtin_amdgcn_fmed3f(ixmin, 1.0f, 258.0f);
    ixmax = __builtin_amdgcn_fmed3f(ixmax, 1.0f, 258.0f);
    iymin = __builtin_amdgcn_fmed3f(iymin, 0.0f, 257.0f);
    iymax = __builtin_amdgcn_fmed3f(iymax, 0.0f, 257.0f);

    const int gx0 = ((int)floorf(ixmin)) & ~1;        // even -> aligned float2 staging
    const int gy0 = (int)floorf(iymin);
    // safety caps (no-op for t1<=77; bound LDS for untested index<2)
    ixmax = fminf(ixmax, (float)(gx0 + 101));
    iymax = fminf(iymax, (float)(gy0 + 100));
    const int gx1 = (int)floorf(ixmax) + 1;           // width_h = gx1-gx0+1 <= 103
    const int gy1 = (int)floorf(iymax) + 1;           // nrows   = gy1-gy0+1 <= 102
    const int width_h = gx1 - gx0 + 1;
    const int nrows = gy1 - gy0 + 1;
    const int wpr = ((width_h - 1) >> 1) + 2;         // words staged per row (<=53)
    const int stride = wpr | 1;                       // odd word stride (<=53)

    // ---- stage window -> LDS fp16 (validity selects create guard zeros) ----
    {
        const float* __restrict__ img = x + (size_t)n * W * W;
        const int ncell = nrows * 64;
        for (int i = tid; i < ncell; i += 256) {
            const int row = i >> 6, w = i & 63;
            if (w < wpr) {
                const int py = gy0 + row - 1;          // pixel row
                const int px = gx0 - 2 + 2 * w;        // pixel x (even)
                const bool vr = (unsigned)py < 256u;
                const bool v0 = vr && ((unsigned)px < 256u);
                const bool v1 = vr && ((unsigned)(px + 1) < 256u);
                const int pyc = min(max(py, 0), 255);
                const int pxc = min(max(px, 0), 254);  // even -> 8B aligned
                const float2 f2 = *(const float2*)(img + pyc * W + pxc);
                const float f0 = v0 ? f2.x : 0.0f;
                const float f1 = v1 ? f2.y : 0.0f;
                const __half2 hp = __floats2half2_rn(f0, f1);
                sw[row * stride + w] = *(const unsigned*)&hp;
            }
        }
    }
    __syncthreads();

    // ---- tap loop (exact ownership, no overshoot) ----
    const int c = cq * 64 + cl;
    const float xc = ((2.0f * (float)c + 1.0f) * (1.0f / 256.0f)) - 1.0f;
    const float bx = fmaf(128.0f * ca, xc, 129.5f);
    const float by = fmaf(-128.0f * sa, xc, 128.5f);
    const int chunk = (t1 + 3) >> 2;
    const int rs = rA + s * chunk;
    const int re = min(rs + chunk, rA + t1);
    const int w0 = r0hi - r0lo;

    float sum0 = 0.0f, sum1 = 0.0f;
    float rfk = (float)rs - 127.5f;

    #pragma unroll 4
    for (int r = rs; r < re; ++r, rfk += 1.0f) {
        float ix = fmaf(sa, rfk, bx);
        float iy = fmaf(ca, rfk, by);
        ix = __builtin_amdgcn_fmed3f(ix, ixmin, ixmax);   // == global [1,258] clamp
        iy = __builtin_amdgcn_fmed3f(iy, iymin, iymax);   // == global [0,257] clamp
        const float wx = __builtin_amdgcn_fractf(ix);
        const float wy = __builtin_amdgcn_fractf(iy);
        const int x0 = (int)ix;
        const int y0 = (int)iy;
        const int lh = x0 - gx0;
        const int lr = y0 - gy0;
        const int sh = (lh & 1) << 4;
        const unsigned* p = sw + lr * stride + (lh >> 1);
        const unsigned A0 = p[0];
        const unsigned B0 = p[1];
        const unsigned A1 = p[stride];
        const unsigned B1 = p[stride + 1];
        const unsigned q0 = (unsigned)(((((unsigned long long)B0) << 32) | A0) >> sh);
        const unsigned q1 = (unsigned)(((((unsigned long long)B1) << 32) | A1) >> sh);
        const __half2 h0 = *(const __half2*)&q0;
        const __half2 h1 = *(const __half2*)&q1;
        const float v00 = __low2float(h0), v01 = __high2float(h0);
        const float v10 = __low2float(h1), v11 = __high2float(h1);
        const float top = fmaf(wx, v01 - v00, v00);
        const float bot = fmaf(wx, v11 - v10, v10);
        const float val = fmaf(wy, bot - top, top);
        sum1 += val;
        if ((unsigned)(r - r0lo) <= (unsigned)w0) sum0 += val;
    }

    // ---- reduce 4 partials; reuse sw as scratch ----
    __syncthreads();
    float* red = (float*)sw;           // 512 floats
    red[s * 64 + cl] = sum0;
    red[256 + s * 64 + cl] = sum1;
    __syncthreads();

    if (s == 0) {
        const float a0 = red[cl] + red[64 + cl] + red[128 + cl] + red[192 + cl];
        const float a1 = red[256 + cl] + red[320 + cl] + red[384 + cl] + red[448 + cl];
        // two contributors (rh=0,1): fp add commutative -> deterministic
        atomicAdd(out + (((size_t)n * 2 + 0) * W + c) * NA + a, a0 * (1.0f / (float)(2 * t0)));
        atomicAdd(out + (((size_t)n * 2 + 1) * W + c) * NA + a, a1 * (1.0f / (float)(2 * t1)));
    }
}

extern "C" void kernel_launch(void* const* d_in, const int* in_sizes, int n_in,
                              void* d_out, int out_size, void* d_ws, size_t ws_size,
                              hipStream_t stream) {
    const float* x = (const float*)d_in[0];
    const int* index_p = (const int*)d_in[1];
    float* out = (float*)d_out;
    const int N = in_sizes[0] / (W * W); // 4

    hipMemsetAsync(d_out, 0, (size_t)out_size * sizeof(float), stream);

    dim3 grid(NA, N, 8);               // 4 column-quarters x 2 r-halves
    radon_kernel<<<grid, 256, 0, stream>>>(x, index_p, out);
}

// Round 19
// 44.868 us; speedup vs baseline: 1.4199x; 1.4199x over previous
//
#include <hip/hip_runtime.h>
#include <hip/hip_fp16.h>

#define W 256
#define NA 180
#define SPLIT 4
#define RWORDS 145            // words per row; odd stride -> axis walks spread over banks
#define ROWBYTES 580
#define ROWS 259              // data rows 1..256 (pixel y + 1); data cols (halfs) 2..257 (pixel x + 2)

__global__ __launch_bounds__(1024) void radon_kernel(
    const float* __restrict__ x, const int* __restrict__ index_p,
    float* __restrict__ out)
{
    __shared__ unsigned sw[ROWS * RWORDS];   // 150,220 B

    const int a = blockIdx.x;        // angle 0..179
    const int n = blockIdx.y;        // batch
    const int tid = threadIdx.x;
    const int c = tid & (W - 1);     // column 0..255
    const int s = tid >> 8;          // r-chunk 0..3 (wave-uniform)

    const float* __restrict__ img = x + (size_t)n * W * W;

    // ---- guard zero-fill (cells disjoint from staged data -> one barrier total) ----
    if (tid < 435) {                       // rows 0,257,258: 3 x 145 words
        const int rr = tid / 145;
        const int w = tid - rr * 145;
        const int row = (rr == 0) ? 0 : (256 + rr);
        sw[row * RWORDS + w] = 0u;
    } else if (tid < 947) {                // col guard words 0,129 rows 1..256
        const int i = tid - 435;
        const int row = 1 + (i >> 1);
        const int w = (i & 1) ? 129 : 0;
        sw[row * RWORDS + w] = 0u;
    }

    // ---- stage image -> LDS fp16 ----
    {
        const float4* img4 = (const float4*)img;
        #pragma unroll
        for (int k = 0; k < 16; ++k) {
            const int g = k * 1024 + tid;
            const int row = (g >> 6) + 1;      // 1..256
            const int m = g & 63;
            const float4 v = img4[g];
            const __half2 h01 = __floats2half2_rn(v.x, v.y);
            const __half2 h23 = __floats2half2_rn(v.z, v.w);
            sw[row * RWORDS + 2 * m + 1] = *(const unsigned*)&h01;  // halfs 4m+2,4m+3
            sw[row * RWORDS + 2 * m + 2] = *(const unsigned*)&h23;
        }
    }
    __syncthreads();

    const int index = *index_p;
    const int seg[6] = {1, 26, 51, 77, 102, 128};
    const int t0 = seg[4 - index];
    const int t1 = seg[4 - index + 1];

    float sa, ca;
    sincosf((float)a * 0.017453292519943295f, &sa, &ca);

    const float xc = ((2.0f * (float)c + 1.0f) * (1.0f / (float)W)) - 1.0f;
    const float bx = fmaf(128.0f * ca, xc, 129.5f);   // +2 x bias (halfs)
    const float by = fmaf(-128.0f * sa, xc, 128.5f);  // +1 y bias (rows)

    const int r1lo = 128 - t1;
    const int r0lo = 128 - t0, r0hi = 127 + t0;
    const int total = 2 * t1;
    const int chunk = (total + SPLIT - 1) / SPLIT;
    const int rs = r1lo + s * chunk;
    const int re = min(rs + chunk, r1lo + total);

#define TAP_BODY                                                              \
        float ix = fmaf(sa, rf, bx);                                          \
        float iy = fmaf(ca, rf, by);                                          \
        ix = __builtin_amdgcn_fmed3f(ix, 1.0f, 258.0f);                       \
        iy = __builtin_amdgcn_fmed3f(iy, 0.0f, 257.0f);                       \
        const float wx = __builtin_amdgcn_fractf(ix);                         \
        const float wy = __builtin_amdgcn_fractf(iy);                         \
        const int x0 = (int)ix;                                               \
        const int y0 = (int)iy;                                               \
        const int wi = y0 * RWORDS + (x0 >> 1);   /* v_mad_u32_u24 */         \
        const unsigned A0 = sw[wi];                                           \
        const unsigned B0 = sw[wi + 1];                                       \
        const unsigned A1 = sw[wi + RWORDS];                                  \
        const unsigned B1 = sw[wi + RWORDS + 1];                              \
        const int sh = (x0 & 1) << 4;                                         \
        const unsigned q0 = __builtin_amdgcn_alignbit(B0, A0, sh);            \
        const unsigned q1 = __builtin_amdgcn_alignbit(B1, A1, sh);            \
        const __half2 h0 = *(const __half2*)&q0;  /* (v00, v01) row y0 */     \
        const __half2 h1 = *(const __half2*)&q1;  /* (v10, v11) row y0+1 */   \
        const __half2 wy2 = __float2half2_rn(wy);                             \
        const __half2 t = __hfma2(wy2, __hsub2(h1, h0), h0);                  \
        const float tl = __low2float(t);                                      \
        const float th = __high2float(t);                                     \
        const float val = fmaf(wx, th - tl, tl);

    float sumA = 0.0f, sumB = 0.0f, sumC = 0.0f;

    // segment A: [rs, min(re, r0lo)) -> outer only
    {
        const int e = min(re, r0lo);
        float rf = (float)rs - 127.5f;
        #pragma unroll 8
        for (int r = rs; r < e; ++r, rf += 1.0f) { TAP_BODY sumA += val; }
    }
    // segment B: [max(rs, r0lo), min(re, r0hi+1)) -> both masks
    {
        const int b = max(rs, r0lo);
        const int e = min(re, r0hi + 1);
        float rf = (float)b - 127.5f;
        #pragma unroll 8
        for (int r = b; r < e; ++r, rf += 1.0f) { TAP_BODY sumB += val; }
    }
    // segment C: [max(rs, r0hi+1), re) -> outer only
    {
        const int b = max(rs, r0hi + 1);
        float rf = (float)b - 127.5f;
        #pragma unroll 8
        for (int r = b; r < re; ++r, rf += 1.0f) { TAP_BODY sumC += val; }
    }
#undef TAP_BODY

    const float sum0 = sumB;
    const float sum1 = sumA + sumB + sumC;

    // ---- reduce partials; reuse sw as scratch ----
    __syncthreads();
    float* red = (float*)sw;                 // 8 KB of 150 KB
    red[(0 * SPLIT + s) * W + c] = sum0;
    red[(1 * SPLIT + s) * W + c] = sum1;
    __syncthreads();

    if (s == 0) {
        const float acc0 = red[0 * W + c] + red[1 * W + c] + red[2 * W + c] + red[3 * W + c];
        const float* r1p = red + SPLIT * W;
        const float acc1 = r1p[0 * W + c] + r1p[1 * W + c] + r1p[2 * W + c] + r1p[3 * W + c];
        out[(((size_t)n * 2 + 0) * W + c) * NA + a] = acc0 * (1.0f / (float)(2 * t0));
        out[(((size_t)n * 2 + 1) * W + c) * NA + a] = acc1 * (1.0f / (float)(2 * t1));
    }
}

extern "C" void kernel_launch(void* const* d_in, const int* in_sizes, int n_in,
                              void* d_out, int out_size, void* d_ws, size_t ws_size,
                              hipStream_t stream) {
    const float* x = (const float*)d_in[0];
    const int* index_p = (const int*)d_in[1];
    float* out = (float*)d_out;
    const int N = in_sizes[0] / (W * W); // 4
    dim3 grid(NA, N);
    radon_kernel<<<grid, 1024, 0, stream>>>(x, index_p, out);
}